// Round 1
// baseline (126.618 us; speedup 1.0000x reference)
//
#include <hip/hip_runtime.h>

#define VR 4
#define NVOX 64            // VR^3
#define NCLS 40
#define NB 64
#define NPTS 100000
#define BPB 16             // blocks per batch
#define G_PER_B (NPTS / 4)        // 25000 groups of 4 points (= 3 float4 each)
#define F4_PER_B (NPTS * 3 / 4)   // 75000 float4 per batch

// Order-preserving float<->uint encoding so we can use integer atomicMin/Max.
__device__ __forceinline__ unsigned fenc(float f) {
    unsigned u = __float_as_uint(f);
    return (u & 0x80000000u) ? ~u : (u ^ 0x80000000u);
}
__device__ __forceinline__ float fdec(unsigned e) {
    unsigned u = (e & 0x80000000u) ? (e ^ 0x80000000u) : ~e;
    return __uint_as_float(u);
}

// Per-batch per-dim min/max. Each thread handles groups of 4 points (12 floats
// = 3 float4 loads) so the dim of every element is static.
__global__ __launch_bounds__(256) void minmax_k(const float4* __restrict__ x,
                                                unsigned* __restrict__ mn_enc,
                                                unsigned* __restrict__ mx_enc) {
    const int b = blockIdx.x / BPB;
    const int sub = blockIdx.x % BPB;
    const float4* xb = x + (size_t)b * F4_PER_B;

    float mn0 = 3.4e38f, mn1 = 3.4e38f, mn2 = 3.4e38f;
    float mx0 = -3.4e38f, mx1 = -3.4e38f, mx2 = -3.4e38f;

    for (int g = sub * 256 + (int)threadIdx.x; g < G_PER_B; g += BPB * 256) {
        float4 a = xb[3 * g];
        float4 c = xb[3 * g + 1];
        float4 e = xb[3 * g + 2];
        // flat index % 3 mapping: a.x->0 a.y->1 a.z->2 a.w->0 c.x->1 c.y->2
        //                         c.z->0 c.w->1 e.x->2 e.y->0 e.z->1 e.w->2
        mn0 = fminf(mn0, fminf(fminf(a.x, a.w), fminf(c.z, e.y)));
        mx0 = fmaxf(mx0, fmaxf(fmaxf(a.x, a.w), fmaxf(c.z, e.y)));
        mn1 = fminf(mn1, fminf(fminf(a.y, c.x), fminf(c.w, e.z)));
        mx1 = fmaxf(mx1, fmaxf(fmaxf(a.y, c.x), fmaxf(c.w, e.z)));
        mn2 = fminf(mn2, fminf(fminf(a.z, c.y), fminf(e.x, e.w)));
        mx2 = fmaxf(mx2, fmaxf(fmaxf(a.z, c.y), fmaxf(e.x, e.w)));
    }

    // wave (64-lane) butterfly reduce
    #pragma unroll
    for (int off = 32; off > 0; off >>= 1) {
        mn0 = fminf(mn0, __shfl_down(mn0, off, 64));
        mn1 = fminf(mn1, __shfl_down(mn1, off, 64));
        mn2 = fminf(mn2, __shfl_down(mn2, off, 64));
        mx0 = fmaxf(mx0, __shfl_down(mx0, off, 64));
        mx1 = fmaxf(mx1, __shfl_down(mx1, off, 64));
        mx2 = fmaxf(mx2, __shfl_down(mx2, off, 64));
    }

    __shared__ float smn[4][3], smx[4][3];
    const int lane = threadIdx.x & 63;
    const int wv = threadIdx.x >> 6;
    if (lane == 0) {
        smn[wv][0] = mn0; smn[wv][1] = mn1; smn[wv][2] = mn2;
        smx[wv][0] = mx0; smx[wv][1] = mx1; smx[wv][2] = mx2;
    }
    __syncthreads();
    if (threadIdx.x < 3) {
        const int d = threadIdx.x;
        float a = smn[0][d], z = smx[0][d];
        #pragma unroll
        for (int w = 1; w < 4; w++) {
            a = fminf(a, smn[w][d]);
            z = fmaxf(z, smx[w][d]);
        }
        atomicMin(&mn_enc[b * 3 + d], fenc(a));
        atomicMax(&mx_enc[b * 3 + d], fenc(z));
    }
}

__device__ __forceinline__ int bin1(float v, float mn, float s4) {
    // v >= mn and s4 > 0  ->  t >= 0, so trunc == floor; clamp high side only.
    int i = (int)((v - mn) * s4);
    return i > (VR - 1) ? (VR - 1) : i;
}

__global__ __launch_bounds__(256) void hist_k(const float4* __restrict__ x,
                                              const unsigned* __restrict__ mn_enc,
                                              const unsigned* __restrict__ mx_enc,
                                              unsigned* __restrict__ hist) {
    const int b = blockIdx.x / BPB;
    const int sub = blockIdx.x % BPB;
    const float4* xb = x + (size_t)b * F4_PER_B;

    __shared__ unsigned lh[NVOX];
    if (threadIdx.x < NVOX) lh[threadIdx.x] = 0;

    float mnv[3], s4[3];
    #pragma unroll
    for (int d = 0; d < 3; d++) {
        float mnf = fdec(mn_enc[b * 3 + d]);
        float mxf = fdec(mx_enc[b * 3 + d]);
        mnv[d] = mnf;
        s4[d] = (float)VR / (mxf - mnf);
    }
    __syncthreads();

    for (int g = sub * 256 + (int)threadIdx.x; g < G_PER_B; g += BPB * 256) {
        float4 a = xb[3 * g];
        float4 c = xb[3 * g + 1];
        float4 e = xb[3 * g + 2];
        // points: (a.x,a.y,a.z) (a.w,c.x,c.y) (c.z,c.w,e.x) (e.y,e.z,e.w)
        int v0 = bin1(a.x, mnv[0], s4[0]) * 16 + bin1(a.y, mnv[1], s4[1]) * 4 + bin1(a.z, mnv[2], s4[2]);
        int v1 = bin1(a.w, mnv[0], s4[0]) * 16 + bin1(c.x, mnv[1], s4[1]) * 4 + bin1(c.y, mnv[2], s4[2]);
        int v2 = bin1(c.z, mnv[0], s4[0]) * 16 + bin1(c.w, mnv[1], s4[1]) * 4 + bin1(e.x, mnv[2], s4[2]);
        int v3 = bin1(e.y, mnv[0], s4[0]) * 16 + bin1(e.z, mnv[1], s4[1]) * 4 + bin1(e.w, mnv[2], s4[2]);
        atomicAdd(&lh[v0], 1u);
        atomicAdd(&lh[v1], 1u);
        atomicAdd(&lh[v2], 1u);
        atomicAdd(&lh[v3], 1u);
    }
    __syncthreads();
    if (threadIdx.x < NVOX) atomicAdd(&hist[b * NVOX + threadIdx.x], lh[threadIdx.x]);
}

__global__ __launch_bounds__(256) void gemv_k(const unsigned* __restrict__ hist,
                                              const float* __restrict__ W,
                                              const float* __restrict__ bias,
                                              float* __restrict__ out) {
    int gid = blockIdx.x * 256 + threadIdx.x;
    if (gid >= NB * NCLS) return;
    int b = gid / NCLS;
    int c = gid - b * NCLS;
    const unsigned* h = hist + b * NVOX;
    const float* w = W + c * NVOX;
    float s = 0.f;
    #pragma unroll
    for (int f = 0; f < NVOX; f++) s += (float)h[f] * w[f];
    out[gid] = s * (1.0f / (float)NPTS) + bias[c];
}

extern "C" void kernel_launch(void* const* d_in, const int* in_sizes, int n_in,
                              void* d_out, int out_size, void* d_ws, size_t ws_size,
                              hipStream_t stream) {
    const float* x = (const float*)d_in[0];      // (64, 100000, 3) fp32
    const float* W = (const float*)d_in[1];      // (40, 64) fp32
    const float* bias = (const float*)d_in[2];   // (40,) fp32
    float* out = (float*)d_out;                  // (64, 40) fp32

    // ws layout: mn_enc [NB*3], mx_enc [NB*3], hist [NB*NVOX]  (all u32)
    unsigned* mn_enc = (unsigned*)d_ws;
    unsigned* mx_enc = mn_enc + NB * 3;
    unsigned* hist = mx_enc + NB * 3;

    // init: encoded-min accumulators to 0xFFFFFFFF, encoded-max + hist to 0
    hipMemsetAsync(d_ws, 0xFF, NB * 3 * sizeof(unsigned), stream);
    hipMemsetAsync((char*)d_ws + NB * 3 * sizeof(unsigned), 0,
                   (NB * 3 + NB * NVOX) * sizeof(unsigned), stream);

    minmax_k<<<NB * BPB, 256, 0, stream>>>((const float4*)x, mn_enc, mx_enc);
    hist_k<<<NB * BPB, 256, 0, stream>>>((const float4*)x, mn_enc, mx_enc, hist);
    gemv_k<<<(NB * NCLS + 255) / 256, 256, 0, stream>>>(hist, W, bias, out);
}

// Round 2
// 125.813 us; speedup vs baseline: 1.0064x; 1.0064x over previous
//
#include <hip/hip_runtime.h>

#define VR 4
#define NVOX 64            // VR^3
#define NCLS 40
#define NB 64
#define NPTS 100000
#define BPB 16             // blocks per batch
#define G_PER_B (NPTS / 4)        // 25000 groups of 4 points (= 3 float4 each)
#define F4_PER_B (NPTS * 3 / 4)   // 75000 float4 per batch
#define STRIDE_G (BPB * 256)      // 4096 groups per grid-stride step
#define FLT_BIG 3.402823466e38f

// ---------------------------------------------------------------------------
// Pass 1: per-batch per-dim min/max -> private partial slots (no atomics, no
// init needed: every slot is unconditionally written by exactly one block).
// ---------------------------------------------------------------------------
__global__ __launch_bounds__(256) void minmax_k(const float4* __restrict__ x,
                                                float* __restrict__ pmin,
                                                float* __restrict__ pmax) {
    const int b = blockIdx.x / BPB;
    const int sub = blockIdx.x % BPB;
    const float4* xb = x + (size_t)b * F4_PER_B;

    float mn0 = FLT_BIG, mn1 = FLT_BIG, mn2 = FLT_BIG;
    float mx0 = -FLT_BIG, mx1 = -FLT_BIG, mx2 = -FLT_BIG;

    for (int base = sub * 256; base < G_PER_B; base += STRIDE_G) {
        int g = base + (int)threadIdx.x;
        bool valid = g < G_PER_B;
        int gc = valid ? g : (G_PER_B - 1);
        float4 a = xb[3 * gc];
        float4 c = xb[3 * gc + 1];
        float4 e = xb[3 * gc + 2];
        if (valid) {
            // flat%3: a.x->0 a.y->1 a.z->2 a.w->0 c.x->1 c.y->2
            //         c.z->0 c.w->1 e.x->2 e.y->0 e.z->1 e.w->2
            mn0 = fminf(mn0, fminf(fminf(a.x, a.w), fminf(c.z, e.y)));
            mx0 = fmaxf(mx0, fmaxf(fmaxf(a.x, a.w), fmaxf(c.z, e.y)));
            mn1 = fminf(mn1, fminf(fminf(a.y, c.x), fminf(c.w, e.z)));
            mx1 = fmaxf(mx1, fmaxf(fmaxf(a.y, c.x), fmaxf(c.w, e.z)));
            mn2 = fminf(mn2, fminf(fminf(a.z, c.y), fminf(e.x, e.w)));
            mx2 = fmaxf(mx2, fmaxf(fmaxf(a.z, c.y), fmaxf(e.x, e.w)));
        }
    }

    #pragma unroll
    for (int off = 32; off > 0; off >>= 1) {
        mn0 = fminf(mn0, __shfl_down(mn0, off, 64));
        mn1 = fminf(mn1, __shfl_down(mn1, off, 64));
        mn2 = fminf(mn2, __shfl_down(mn2, off, 64));
        mx0 = fmaxf(mx0, __shfl_down(mx0, off, 64));
        mx1 = fmaxf(mx1, __shfl_down(mx1, off, 64));
        mx2 = fmaxf(mx2, __shfl_down(mx2, off, 64));
    }

    __shared__ float smn[4][3], smx[4][3];
    const int lane = threadIdx.x & 63;
    const int wv = threadIdx.x >> 6;
    if (lane == 0) {
        smn[wv][0] = mn0; smn[wv][1] = mn1; smn[wv][2] = mn2;
        smx[wv][0] = mx0; smx[wv][1] = mx1; smx[wv][2] = mx2;
    }
    __syncthreads();
    if (threadIdx.x < 3) {
        const int d = threadIdx.x;
        float a = smn[0][d], z = smx[0][d];
        #pragma unroll
        for (int w = 1; w < 4; w++) {
            a = fminf(a, smn[w][d]);
            z = fmaxf(z, smx[w][d]);
        }
        pmin[(b * BPB + sub) * 3 + d] = a;
        pmax[(b * BPB + sub) * 3 + d] = z;
    }
}

// ---------------------------------------------------------------------------
// Pass 2: histogram via ballot counting. Lane L of each wave owns the count
// of voxel L: per point, 6 ballots of the voxel-id bits; lane L ANDs the
// (complemented-per-its-own-bits) masks and popcounts. Zero atomics,
// distribution-independent cost.
// ---------------------------------------------------------------------------
__device__ __forceinline__ int bin1(float v, float mn, float s4) {
    int i = (int)((v - mn) * s4);   // v>=mn, s4>0 -> trunc==floor
    return i > (VR - 1) ? (VR - 1) : i;
}

__device__ __forceinline__ void tally(int v, unsigned long long vm,
                                      const unsigned long long* ns,
                                      unsigned& cnt) {
    unsigned long long b0 = __ballot(v & 1);
    unsigned long long b1 = __ballot(v & 2);
    unsigned long long b2 = __ballot(v & 4);
    unsigned long long b3 = __ballot(v & 8);
    unsigned long long b4 = __ballot(v & 16);
    unsigned long long b5 = __ballot(v & 32);
    unsigned long long m = vm & (b0 ^ ns[0]) & (b1 ^ ns[1]) & (b2 ^ ns[2])
                              & (b3 ^ ns[3]) & (b4 ^ ns[4]) & (b5 ^ ns[5]);
    cnt += (unsigned)__popcll(m);
}

__global__ __launch_bounds__(256) void hist_k(const float4* __restrict__ x,
                                              const float* __restrict__ pmin,
                                              const float* __restrict__ pmax,
                                              unsigned* __restrict__ phist) {
    const int b = blockIdx.x / BPB;
    const int sub = blockIdx.x % BPB;
    const float4* xb = x + (size_t)b * F4_PER_B;
    const int lane = threadIdx.x & 63;
    const int wv = threadIdx.x >> 6;

    // reduce the 16 min/max partials for this batch
    __shared__ float smm[6];   // mn0 mn1 mn2 mx0 mx1 mx2
    if (threadIdx.x < 6) {
        int d = threadIdx.x % 3;
        bool isMax = threadIdx.x >= 3;
        float r = isMax ? -FLT_BIG : FLT_BIG;
        for (int s = 0; s < BPB; s++) {
            float v = isMax ? pmax[(b * BPB + s) * 3 + d]
                            : pmin[(b * BPB + s) * 3 + d];
            r = isMax ? fmaxf(r, v) : fminf(r, v);
        }
        smm[threadIdx.x] = r;
    }
    __syncthreads();
    const float mn_0 = smm[0], mn_1 = smm[1], mn_2 = smm[2];
    const float s4_0 = (float)VR / (smm[3] - smm[0]);
    const float s4_1 = (float)VR / (smm[4] - smm[1]);
    const float s4_2 = (float)VR / (smm[5] - smm[2]);

    unsigned long long ns[6];
    #pragma unroll
    for (int k = 0; k < 6; k++)
        ns[k] = ((lane >> k) & 1) ? 0ull : ~0ull;

    unsigned cnt = 0;
    for (int base = sub * 256; base < G_PER_B; base += STRIDE_G) {
        int g = base + (int)threadIdx.x;
        bool valid = g < G_PER_B;
        int gc = valid ? g : (G_PER_B - 1);
        float4 a = xb[3 * gc];
        float4 c = xb[3 * gc + 1];
        float4 e = xb[3 * gc + 2];
        unsigned long long vm = __ballot(valid);
        // points: (a.x,a.y,a.z) (a.w,c.x,c.y) (c.z,c.w,e.x) (e.y,e.z,e.w)
        int v0 = bin1(a.x, mn_0, s4_0) * 16 + bin1(a.y, mn_1, s4_1) * 4 + bin1(a.z, mn_2, s4_2);
        int v1 = bin1(a.w, mn_0, s4_0) * 16 + bin1(c.x, mn_1, s4_1) * 4 + bin1(c.y, mn_2, s4_2);
        int v2 = bin1(c.z, mn_0, s4_0) * 16 + bin1(c.w, mn_1, s4_1) * 4 + bin1(e.x, mn_2, s4_2);
        int v3 = bin1(e.y, mn_0, s4_0) * 16 + bin1(e.z, mn_1, s4_1) * 4 + bin1(e.w, mn_2, s4_2);
        tally(v0, vm, ns, cnt);
        tally(v1, vm, ns, cnt);
        tally(v2, vm, ns, cnt);
        tally(v3, vm, ns, cnt);
    }

    __shared__ unsigned swh[4][NVOX];
    swh[wv][lane] = cnt;
    __syncthreads();
    if (threadIdx.x < NVOX) {
        phist[(b * BPB + sub) * NVOX + threadIdx.x] =
            swh[0][threadIdx.x] + swh[1][threadIdx.x] +
            swh[2][threadIdx.x] + swh[3][threadIdx.x];
    }
}

// ---------------------------------------------------------------------------
// Pass 3: reduce the 16 hist partials per batch + 40x64 GEMV, one block/batch.
// ---------------------------------------------------------------------------
__global__ __launch_bounds__(256) void gemv_k(const unsigned* __restrict__ phist,
                                              const float* __restrict__ W,
                                              const float* __restrict__ bias,
                                              float* __restrict__ out) {
    const int b = blockIdx.x;
    __shared__ float fh[NVOX];
    __shared__ float sW[NCLS * NVOX];

    if (threadIdx.x < NVOX) {
        unsigned s = 0;
        for (int p = 0; p < BPB; p++)
            s += phist[(b * BPB + p) * NVOX + threadIdx.x];
        fh[threadIdx.x] = (float)s * (1.0f / (float)NPTS);
    }
    for (int i = threadIdx.x; i < NCLS * NVOX; i += 256)
        sW[i] = W[i];
    __syncthreads();

    if (threadIdx.x < NCLS) {
        const int c = threadIdx.x;
        float acc = 0.f;
        #pragma unroll
        for (int f = 0; f < NVOX; f++)
            acc += fh[f] * sW[c * NVOX + f];
        out[b * NCLS + c] = acc + bias[c];
    }
}

extern "C" void kernel_launch(void* const* d_in, const int* in_sizes, int n_in,
                              void* d_out, int out_size, void* d_ws, size_t ws_size,
                              hipStream_t stream) {
    const float* x = (const float*)d_in[0];      // (64, 100000, 3) fp32
    const float* W = (const float*)d_in[1];      // (40, 64) fp32
    const float* bias = (const float*)d_in[2];   // (40,) fp32
    float* out = (float*)d_out;                  // (64, 40) fp32

    // ws layout (all slots fully overwritten every call -> no init needed):
    //   pmin  : NB*BPB*3 f32
    //   pmax  : NB*BPB*3 f32
    //   phist : NB*BPB*64 u32
    float* pmin = (float*)d_ws;
    float* pmax = pmin + NB * BPB * 3;
    unsigned* phist = (unsigned*)(pmax + NB * BPB * 3);

    minmax_k<<<NB * BPB, 256, 0, stream>>>((const float4*)x, pmin, pmax);
    hist_k<<<NB * BPB, 256, 0, stream>>>((const float4*)x, pmin, pmax, phist);
    gemv_k<<<NB, 256, 0, stream>>>(phist, W, bias, out);
}